// Round 5
// baseline (410.877 us; speedup 1.0000x reference)
//
#include <hip/hip_runtime.h>
#include <hip/hip_bf16.h>
#include <stdint.h>
#include <stddef.h>

typedef __bf16 bf16;
typedef __bf16 bf16x4 __attribute__((ext_vector_type(4)));
typedef __bf16 bf16x8 __attribute__((ext_vector_type(8)));
typedef float  f32x4  __attribute__((ext_vector_type(4)));

#define LOG2E 1.44269504f
#define QSCALE 0.18033688f   /* 0.125 * log2(e) */

// ---------------------------------------------------------------- helpers
__device__ __forceinline__ void gld_lds16(const void* gptr, void* lptr) {
    __builtin_amdgcn_global_load_lds(
        (const __attribute__((address_space(1))) unsigned int*)gptr,
        (__attribute__((address_space(3))) unsigned int*)lptr,
        16, 0, 0);
}

// ---------------------------------------------------------------- merged cast
// blocks [0,6144): g -> g_bf ; [6144,6720): wq ; [6720,7296): wk ; [7296,9600): w_hn
__global__ void cast_all(const float* __restrict__ g, const float* __restrict__ wq,
                         const float* __restrict__ wk, const float* __restrict__ whn,
                         bf16* __restrict__ g_bf, bf16* __restrict__ Wcat) {
    int b = blockIdx.x;
    const float* src; bf16* dst; int off;
    if (b < 6144)      { src = g;   dst = g_bf;           off = 0;    }
    else if (b < 6720) { src = wq;  dst = Wcat;           off = 6144; }
    else if (b < 7296) { src = wk;  dst = Wcat + 589824;  off = 6720; }
    else               { src = whn; dst = Wcat + 1179648; off = 7296; }
    int i = ((b - off) * 256 + threadIdx.x) * 4;
    float4 v = *(const float4*)(src + i);
    bf16x4 o = { (bf16)v.x, (bf16)v.y, (bf16)v.z, (bf16)v.w };
    *(bf16x4*)(dst + i) = o;
}

// zero rowsum(8192) + arow(98304) contiguous, plus out[0].  grid 416 x 256.
__global__ void zero_ws(float* __restrict__ sums, float* __restrict__ out) {
    int i = blockIdx.x * 256 + threadIdx.x;
    sums[i] = 0.f;
    if (i == 0) out[0] = 0.f;
}

// ---------------------------------------------------------------- fused NT GEMM
// C_full[M, 4608] = A[M,768] * Wcat[4608,768]^T  (bf16 in, fp32 acc), 16x16x32 MFMA
// cols [0,768): q -> store QSCALE*acc ; [768,1536): k -> store acc
// cols [1536,4608): Hopfield -> per-row sum exp2(beta*log2e*acc) via atomicAdd
// BM=BN=128, BK=64, 256 threads (2x2 waves, 64x64 each).
// LDS [row][seg] with XOR swizzle: slot s holds global seg s^(row&7).
__global__ void gemm_fused(const bf16* __restrict__ A, const bf16* __restrict__ Bm,
                           bf16* __restrict__ qk, float* __restrict__ rowsum,
                           const float* __restrict__ beta_p) {
    __shared__ __align__(16) bf16 As[128 * 64];
    __shared__ __align__(16) bf16 Bs[128 * 64];
    const int t = threadIdx.x;
    const int w = t >> 6, l = t & 63;
    const int wm = (w >> 1) * 64, wn = (w & 1) * 64;
    const int tile_m = blockIdx.x * 128;
    const int tile_n = blockIdx.y * 128;

    f32x4 acc[4][4];
#pragma unroll
    for (int i = 0; i < 4; i++)
#pragma unroll
        for (int j = 0; j < 4; j++)
#pragma unroll
            for (int q = 0; q < 4; q++) acc[i][j][q] = 0.f;

    const int srow = t >> 3;               // 0..31
    const int sswz = (t & 7) ^ (srow & 7); // swizzled global segment
    const bf16* gA = A  + (size_t)(tile_m + srow) * 768 + sswz * 8;
    const bf16* gB = Bm + (size_t)(tile_n + srow) * 768 + sswz * 8;

    const int fr = l & 15, fg = l >> 4;

    for (int k0 = 0; k0 < 768; k0 += 64) {
#pragma unroll
        for (int i = 0; i < 4; i++) {
            gld_lds16(gA + (size_t)i * 32 * 768 + k0, As + (i * 256 + t) * 8);
            gld_lds16(gB + (size_t)i * 32 * 768 + k0, Bs + (i * 256 + t) * 8);
        }
        __builtin_amdgcn_s_waitcnt(0);
        __syncthreads();

#pragma unroll
        for (int ks = 0; ks < 2; ks++) {
            const int swz = (((ks * 4 + fg) ^ (fr & 7))) * 8;  // row&7 == fr&7
            bf16x8 af[4], bfr[4];
#pragma unroll
            for (int i = 0; i < 4; i++) {
                af[i]  = *(const bf16x8*)(As + (wm + i * 16 + fr) * 64 + swz);
                bfr[i] = *(const bf16x8*)(Bs + (wn + i * 16 + fr) * 64 + swz);
            }
#pragma unroll
            for (int i = 0; i < 4; i++)
#pragma unroll
                for (int j = 0; j < 4; j++)
                    acc[i][j] = __builtin_amdgcn_mfma_f32_16x16x32_bf16(af[i], bfr[j], acc[i][j], 0, 0, 0);
        }
        __syncthreads();
    }

    // C/D layout: col=lane&15, row=(lane>>4)*4+reg  [m89-verified]
    const int cr = fg * 4, cc = fr;

    if (tile_n < 1536) {
        const float sc = (tile_n < 768) ? QSCALE : 1.0f;  // block-uniform (768%128==0)
#pragma unroll
        for (int i = 0; i < 4; i++)
#pragma unroll
            for (int j = 0; j < 4; j++)
#pragma unroll
                for (int r = 0; r < 4; r++) {
                    int row = tile_m + wm + i * 16 + cr + r;
                    int col = tile_n + wn + j * 16 + cc;
                    qk[(size_t)row * 1536 + col] = (bf16)(sc * acc[i][j][r]);
                }
    } else {
        const float sc2 = beta_p[0] * LOG2E;
#pragma unroll
        for (int i = 0; i < 4; i++)
#pragma unroll
            for (int r = 0; r < 4; r++) {
                float s = 0.f;
#pragma unroll
                for (int j = 0; j < 4; j++) s += __builtin_amdgcn_exp2f(sc2 * acc[i][j][r]);
                s += __shfl_xor(s, 1, 16);
                s += __shfl_xor(s, 2, 16);
                s += __shfl_xor(s, 4, 16);
                s += __shfl_xor(s, 8, 16);
                if ((l & 15) == 0)
                    atomicAdd(&rowsum[tile_m + wm + i * 16 + cr + r], s);
            }
    }
}

// ---------------------------------------------------------------- attention exp-sums
// QK: [8192,1536] bf16; cols [0,768) = QSCALE-prescaled q, [768,1536) = k.
// grid (qt*2+kh : 16, h : 12, b : 8), 256 thr. Block: 128 q-rows x 512 K-rows.
// Single 16KB LDS buffer: Q staged first (frags -> regs), then 4 x 128-row K chunks.
// LDS [row][seg] XOR-swizzled (slot s holds global seg s^(row&7)) — matches frag reads.
// Partial sum_k exp2(q·k) atomicAdd'ed into arow[(b*12+h)*1024 + qrow].
__global__ void __launch_bounds__(256, 6)
attn_energy(const bf16* __restrict__ QK, float* __restrict__ arow) {
    __shared__ __align__(16) bf16 S[128 * 64];   // 16 KB
    const int t = threadIdx.x, w = t >> 6, l = t & 63;
    const int qt = blockIdx.x >> 1, kh = blockIdx.x & 1;
    const int h = blockIdx.y, b = blockIdx.z;
    const size_t qbase = ((size_t)b * 1024 + qt * 128) * 1536 + h * 64;
    const size_t kbase = ((size_t)b * 1024 + kh * 512) * 1536 + 768 + h * 64;

    const int sr = t >> 3;       // 0..31 (staging row within 32-row group)
    const int sl = t & 7;        // LDS seg slot
    const int fr = l & 15, fg = l >> 4;

    // ---- stage Q tile (128 rows x 64 z), swizzled
#pragma unroll
    for (int i = 0; i < 4; i++) {
        int row = i * 32 + sr;
        gld_lds16(QK + qbase + (size_t)row * 1536 + (sl ^ (row & 7)) * 8,
                  S + (i * 256 + t) * 8);
    }
    __builtin_amdgcn_s_waitcnt(0);
    __syncthreads();

    bf16x8 af[2][2];
#pragma unroll
    for (int mi = 0; mi < 2; mi++)
#pragma unroll
        for (int ks = 0; ks < 2; ks++) {
            int r = w * 32 + mi * 16 + fr;
            af[mi][ks] = *(const bf16x8*)(S + r * 64 + ((ks * 4 + fg) ^ (fr & 7)) * 8);
        }
    __syncthreads();   // all waves done reading Q before overwrite

    float rs[2][4] = {};
    for (int kc = 0; kc < 4; kc++) {
#pragma unroll
        for (int i = 0; i < 4; i++) {
            int row = i * 32 + sr;
            gld_lds16(QK + kbase + (size_t)(kc * 128 + row) * 1536 + (sl ^ (row & 7)) * 8,
                      S + (i * 256 + t) * 8);
        }
        __builtin_amdgcn_s_waitcnt(0);
        __syncthreads();
#pragma unroll
        for (int nt = 0; nt < 8; nt++) {
            int kr = nt * 16 + fr;            // kr&7 == fr&7
            bf16x8 b0 = *(const bf16x8*)(S + kr * 64 + ((0 * 4 + fg) ^ (fr & 7)) * 8);
            bf16x8 b1 = *(const bf16x8*)(S + kr * 64 + ((1 * 4 + fg) ^ (fr & 7)) * 8);
#pragma unroll
            for (int mi = 0; mi < 2; mi++) {
                f32x4 acc;
#pragma unroll
                for (int q = 0; q < 4; q++) acc[q] = 0.f;
                acc = __builtin_amdgcn_mfma_f32_16x16x32_bf16(af[mi][0], b0, acc, 0, 0, 0);
                acc = __builtin_amdgcn_mfma_f32_16x16x32_bf16(af[mi][1], b1, acc, 0, 0, 0);
#pragma unroll
                for (int r = 0; r < 4; r++) rs[mi][r] += __builtin_amdgcn_exp2f(acc[r]);
            }
        }
        __syncthreads();
    }

    // C/D layout: row=(fg*4+reg), col=fr.  Sum over the 16 col-lanes, one atomic/row.
    const int rowbase = (b * 12 + h) * 1024 + qt * 128 + w * 32;
#pragma unroll
    for (int mi = 0; mi < 2; mi++)
#pragma unroll
        for (int r = 0; r < 4; r++) {
            float v = rs[mi][r];
            v += __shfl_xor(v, 1, 16);
            v += __shfl_xor(v, 2, 16);
            v += __shfl_xor(v, 4, 16);
            v += __shfl_xor(v, 8, 16);
            if ((l & 15) == 0)
                atomicAdd(&arow[rowbase + mi * 16 + fg * 4 + r], v);
        }
}

// ---------------------------------------------------------------- merged finalize
// sums = [rowsum(8192) | arow(98304)].  grid 416 x 256 (8192 = 32*256: block-uniform split)
__global__ void finalize(const float* __restrict__ sums, const float* __restrict__ beta_p,
                         float* __restrict__ out) {
    __shared__ float wpart[4];
    const int t = threadIdx.x, w = t >> 6, l = t & 63;
    const int i = blockIdx.x * 256 + t;
    float v;
    if (i < 8192) v = (-1.f / beta_p[0]) * __logf(sums[i]);
    else          v = -8.f * __logf(sums[i]);
    for (int o = 32; o > 0; o >>= 1) v += __shfl_down(v, o, 64);
    if (l == 0) wpart[w] = v;
    __syncthreads();
    if (t == 0) atomicAdd(out, wpart[0] + wpart[1] + wpart[2] + wpart[3]);
}

// ---------------------------------------------------------------- launch
extern "C" void kernel_launch(void* const* d_in, const int* in_sizes, int n_in,
                              void* d_out, int out_size, void* d_ws, size_t ws_size,
                              hipStream_t stream) {
    const float* g    = (const float*)d_in[0];   // [8,1024,768]
    const float* wq   = (const float*)d_in[1];   // [12,64,768]
    const float* wk   = (const float*)d_in[2];   // [12,64,768]
    const float* w_hn = (const float*)d_in[3];   // [3072,768]
    const float* beta = (const float*)d_in[4];   // [1]
    float* out = (float*)d_out;

    char* ws = (char*)d_ws;
    bf16*  g_bf   = (bf16*)(ws);                          // 12,582,912 B
    bf16*  Wcat   = (bf16*)(ws + 12582912);               //  7,077,888 B (4608 x 768)
    bf16*  qk     = (bf16*)(ws + 19660800);               // 25,165,824 B
    float* sums   = (float*)(ws + 44826624);              // rowsum 8192 | arow 98304 (426 KB)
    float* rowsum = sums;
    float* arow   = sums + 8192;

    zero_ws<<<416, 256, 0, stream>>>(sums, out);
    cast_all<<<9600, 256, 0, stream>>>(g, wq, wk, w_hn, g_bf, Wcat);

    dim3 gg(64, 36);   // 8192/128 x 4608/128
    gemm_fused<<<gg, 256, 0, stream>>>(g_bf, Wcat, qk, rowsum, beta);

    dim3 ga(16, 12, 8);   // (qt x kh), h, b
    attn_energy<<<ga, 256, 0, stream>>>(qk, arow);

    finalize<<<416, 256, 0, stream>>>(sums, beta, out);
}

// Round 6
// 177.202 us; speedup vs baseline: 2.3187x; 2.3187x over previous
//
#include <hip/hip_runtime.h>
#include <hip/hip_bf16.h>
#include <stdint.h>
#include <stddef.h>

typedef __bf16 bf16;
typedef __bf16 bf16x4 __attribute__((ext_vector_type(4)));
typedef __bf16 bf16x8 __attribute__((ext_vector_type(8)));
typedef float  f32x4  __attribute__((ext_vector_type(4)));

#define LOG2E 1.44269504f
#define QSCALE 0.18033688f   /* 0.125 * log2(e) */

// ---------------------------------------------------------------- helpers
__device__ __forceinline__ void gld_lds16(const void* gptr, void* lptr) {
    __builtin_amdgcn_global_load_lds(
        (const __attribute__((address_space(1))) unsigned int*)gptr,
        (__attribute__((address_space(3))) unsigned int*)lptr,
        16, 0, 0);
}

// ---------------------------------------------------------------- merged cast + zero
// blocks [0,6144): g -> g_bf ; [6144,6720): wq ; [6720,7296): wk ; [7296,9600): w_hn
// blocks [0,8) additionally zero rowsum (8192 f32); block 0 thread 0 zeroes out[0].
__global__ void cast_all(const float* __restrict__ g, const float* __restrict__ wq,
                         const float* __restrict__ wk, const float* __restrict__ whn,
                         bf16* __restrict__ g_bf, bf16* __restrict__ Wcat,
                         float* __restrict__ rowsum, float* __restrict__ out) {
    int b = blockIdx.x, t = threadIdx.x;
    if (b < 8) {
        float4 z = {0.f, 0.f, 0.f, 0.f};
        *(float4*)(rowsum + (b * 256 + t) * 4) = z;
        if (b == 0 && t == 0) out[0] = 0.f;
    }
    const float* src; bf16* dst; int off;
    if (b < 6144)      { src = g;   dst = g_bf;           off = 0;    }
    else if (b < 6720) { src = wq;  dst = Wcat;           off = 6144; }
    else if (b < 7296) { src = wk;  dst = Wcat + 589824;  off = 6720; }
    else               { src = whn; dst = Wcat + 1179648; off = 7296; }
    int i = ((b - off) * 256 + t) * 4;
    float4 v = *(const float4*)(src + i);
    bf16x4 o = { (bf16)v.x, (bf16)v.y, (bf16)v.z, (bf16)v.w };
    *(bf16x4*)(dst + i) = o;
}

// ---------------------------------------------------------------- fused NT GEMM
// C_full[M, 4608] = A[M,768] * Wcat[4608,768]^T  (bf16 in, fp32 acc), 16x16x32 MFMA
// cols [0,1536): q/k -> store into qkh[b][h][{q,k}][1024][64] with z-segments
//   PRE-SWIZZLED (seg ^= krow&7) so attention can stage linearly. q pre-scaled.
// cols [1536,4608): Hopfield -> per-row sum exp2(beta*log2e*acc) via atomicAdd.
// BM=BN=128, BK=64, 256 threads (2x2 waves, 64x64 each).
// LDS [row][seg] with XOR swizzle on the LDS *image* (staged via swizzled global
// source — fine here: A/W inputs are L2/L3-resident, amplification absorbed).
__global__ void gemm_fused(const bf16* __restrict__ A, const bf16* __restrict__ Bm,
                           bf16* __restrict__ qkh, float* __restrict__ rowsum,
                           const float* __restrict__ beta_p) {
    __shared__ __align__(16) bf16 As[128 * 64];
    __shared__ __align__(16) bf16 Bs[128 * 64];
    const int t = threadIdx.x;
    const int w = t >> 6, l = t & 63;
    const int wm = (w >> 1) * 64, wn = (w & 1) * 64;
    const int tile_m = blockIdx.x * 128;
    const int tile_n = blockIdx.y * 128;

    f32x4 acc[4][4];
#pragma unroll
    for (int i = 0; i < 4; i++)
#pragma unroll
        for (int j = 0; j < 4; j++)
#pragma unroll
            for (int q = 0; q < 4; q++) acc[i][j][q] = 0.f;

    const int srow = t >> 3;               // 0..31
    const int sswz = (t & 7) ^ (srow & 7); // swizzled global segment
    const bf16* gA = A  + (size_t)(tile_m + srow) * 768 + sswz * 8;
    const bf16* gB = Bm + (size_t)(tile_n + srow) * 768 + sswz * 8;

    const int fr = l & 15, fg = l >> 4;

    for (int k0 = 0; k0 < 768; k0 += 64) {
#pragma unroll
        for (int i = 0; i < 4; i++) {
            gld_lds16(gA + (size_t)i * 32 * 768 + k0, As + (i * 256 + t) * 8);
            gld_lds16(gB + (size_t)i * 32 * 768 + k0, Bs + (i * 256 + t) * 8);
        }
        __builtin_amdgcn_s_waitcnt(0);
        __syncthreads();

#pragma unroll
        for (int ks = 0; ks < 2; ks++) {
            const int swz = (((ks * 4 + fg) ^ (fr & 7))) * 8;  // row&7 == fr&7
            bf16x8 af[4], bfr[4];
#pragma unroll
            for (int i = 0; i < 4; i++) {
                af[i]  = *(const bf16x8*)(As + (wm + i * 16 + fr) * 64 + swz);
                bfr[i] = *(const bf16x8*)(Bs + (wn + i * 16 + fr) * 64 + swz);
            }
#pragma unroll
            for (int i = 0; i < 4; i++)
#pragma unroll
                for (int j = 0; j < 4; j++)
                    acc[i][j] = __builtin_amdgcn_mfma_f32_16x16x32_bf16(af[i], bfr[j], acc[i][j], 0, 0, 0);
        }
        __syncthreads();
    }

    // C/D layout: col=lane&15, row=(lane>>4)*4+reg  [m89-verified]
    const int cr = fg * 4, cc = fr;

    if (tile_n < 1536) {
        const int tt = (tile_n >= 768);                    // 0 = q, 1 = k (768%128==0)
        const int hh = (tile_n - tt * 768 + wn) >> 6;      // head (wn spans one head)
        const int bb = tile_m >> 10;
        const int m7 = tile_m & 1023;                      // row base within plane
        const float sc = tt ? 1.0f : QSCALE;
        bf16* base = qkh + ((size_t)(((bb * 12 + hh) * 2 + tt) * 1024 + m7) << 6);
#pragma unroll
        for (int i = 0; i < 4; i++)
#pragma unroll
            for (int r = 0; r < 4; r++) {
                int kr  = wm + i * 16 + cr + r;            // kr&7 == (cr+r)&7
                int swz = (cr + r) & 7;
#pragma unroll
                for (int j = 0; j < 4; j++) {
                    int z   = j * 16 + cc;                 // 0..63
                    int pos = (((z >> 3) ^ swz) << 3) | (z & 7);
                    base[(size_t)kr * 64 + pos] = (bf16)(sc * acc[i][j][r]);
                }
            }
    } else {
        const float sc2 = beta_p[0] * LOG2E;
#pragma unroll
        for (int i = 0; i < 4; i++)
#pragma unroll
            for (int r = 0; r < 4; r++) {
                float s = 0.f;
#pragma unroll
                for (int j = 0; j < 4; j++) s += __builtin_amdgcn_exp2f(sc2 * acc[i][j][r]);
                s += __shfl_xor(s, 1, 16);
                s += __shfl_xor(s, 2, 16);
                s += __shfl_xor(s, 4, 16);
                s += __shfl_xor(s, 8, 16);
                if ((l & 15) == 0)
                    atomicAdd(&rowsum[tile_m + wm + i * 16 + cr + r], s);
            }
    }
}

// ---------------------------------------------------------------- attention exp-sums
// qkh[b][h][{q,k}][1024][64] bf16, z-segments pre-swizzled by (krow&7), q pre-scaled.
// grid (qt:8, h:12, b:8), 256 thr. Block: 128 q-rows x all 1024 K-rows.
// Staging is a LINEAR contiguous global_load_lds copy (full coalescing);
// LDS image is already swizzled -> conflict-free frag reads.
// Double-buffered K chunks (2 x 16 KB): prefetch chunk kc+1 during compute of kc.
// One writer per q-row -> plain store to arow[(b*12+h)*1024 + qrow].
__global__ void __launch_bounds__(256, 4)
attn_energy(const bf16* __restrict__ qkh, float* __restrict__ arow) {
    __shared__ __align__(16) bf16 S[2][128 * 64];   // 32 KB
    const int t = threadIdx.x, w = t >> 6, l = t & 63;
    const int qt = blockIdx.x, h = blockIdx.y, b = blockIdx.z;
    const bf16* qp = qkh + ((size_t)((b * 12 + h) * 2 + 0) << 16) + qt * 128 * 64;
    const bf16* kp = qkh + ((size_t)((b * 12 + h) * 2 + 1) << 16);
    const int fr = l & 15, fg = l >> 4;

    // ---- stage Q tile (16 KB, linear)
#pragma unroll
    for (int i = 0; i < 4; i++)
        gld_lds16(qp + (i * 256 + t) * 8, S[0] + (i * 256 + t) * 8);
    __builtin_amdgcn_s_waitcnt(0);
    __syncthreads();

    bf16x8 af[2][2];
#pragma unroll
    for (int mi = 0; mi < 2; mi++)
#pragma unroll
        for (int ks = 0; ks < 2; ks++) {
            int r = w * 32 + mi * 16 + fr;
            af[mi][ks] = *(const bf16x8*)(S[0] + r * 64 + ((ks * 4 + fg) ^ (fr & 7)) * 8);
        }

    // ---- prefetch K chunk 0 -> S[1]
#pragma unroll
    for (int i = 0; i < 4; i++)
        gld_lds16(kp + (i * 256 + t) * 8, S[1] + (i * 256 + t) * 8);

    float rs[2][4] = {};
    for (int kc = 0; kc < 8; kc++) {
        const bf16* Sc = S[1 - (kc & 1)];
        __builtin_amdgcn_s_waitcnt(0);   // own prefetch of chunk kc done
        __syncthreads();                 // everyone's done (and prev buffer free)
        if (kc < 7) {
            const bf16* src = kp + (kc + 1) * 128 * 64;
            bf16* dstb = (bf16*)S[kc & 1];
#pragma unroll
            for (int i = 0; i < 4; i++)
                gld_lds16(src + (i * 256 + t) * 8, dstb + (i * 256 + t) * 8);
        }
#pragma unroll
        for (int nt = 0; nt < 8; nt++) {
            int kr = nt * 16 + fr;       // kr&7 == fr&7
            bf16x8 b0 = *(const bf16x8*)(Sc + kr * 64 + ((0 + fg) ^ (fr & 7)) * 8);
            bf16x8 b1 = *(const bf16x8*)(Sc + kr * 64 + ((4 + fg) ^ (fr & 7)) * 8);
#pragma unroll
            for (int mi = 0; mi < 2; mi++) {
                f32x4 acc;
#pragma unroll
                for (int q = 0; q < 4; q++) acc[q] = 0.f;
                acc = __builtin_amdgcn_mfma_f32_16x16x32_bf16(af[mi][0], b0, acc, 0, 0, 0);
                acc = __builtin_amdgcn_mfma_f32_16x16x32_bf16(af[mi][1], b1, acc, 0, 0, 0);
#pragma unroll
                for (int r = 0; r < 4; r++) rs[mi][r] += __builtin_amdgcn_exp2f(acc[r]);
            }
        }
    }

    // C/D layout: row=(fg*4+reg), col=fr. Sum over 16 col-lanes; single writer/row.
    const int rowbase = (b * 12 + h) * 1024 + qt * 128 + w * 32;
#pragma unroll
    for (int mi = 0; mi < 2; mi++)
#pragma unroll
        for (int r = 0; r < 4; r++) {
            float v = rs[mi][r];
            v += __shfl_xor(v, 1, 16);
            v += __shfl_xor(v, 2, 16);
            v += __shfl_xor(v, 4, 16);
            v += __shfl_xor(v, 8, 16);
            if ((l & 15) == 0)
                arow[rowbase + mi * 16 + fg * 4 + r] = v;
        }
}

// ---------------------------------------------------------------- merged finalize
// sums = [rowsum(8192) | arow(98304)].  grid 416 x 256 (8192 = 32*256: uniform split)
__global__ void finalize(const float* __restrict__ sums, const float* __restrict__ beta_p,
                         float* __restrict__ out) {
    __shared__ float wpart[4];
    const int t = threadIdx.x, w = t >> 6, l = t & 63;
    const int i = blockIdx.x * 256 + t;
    float v;
    if (i < 8192) v = (-1.f / beta_p[0]) * __logf(sums[i]);
    else          v = -8.f * __logf(sums[i]);
    for (int o = 32; o > 0; o >>= 1) v += __shfl_down(v, o, 64);
    if (l == 0) wpart[w] = v;
    __syncthreads();
    if (t == 0) atomicAdd(out, wpart[0] + wpart[1] + wpart[2] + wpart[3]);
}

// ---------------------------------------------------------------- launch
extern "C" void kernel_launch(void* const* d_in, const int* in_sizes, int n_in,
                              void* d_out, int out_size, void* d_ws, size_t ws_size,
                              hipStream_t stream) {
    const float* g    = (const float*)d_in[0];   // [8,1024,768]
    const float* wq   = (const float*)d_in[1];   // [12,64,768]
    const float* wk   = (const float*)d_in[2];   // [12,64,768]
    const float* w_hn = (const float*)d_in[3];   // [3072,768]
    const float* beta = (const float*)d_in[4];   // [1]
    float* out = (float*)d_out;

    char* ws = (char*)d_ws;
    bf16*  g_bf   = (bf16*)(ws);                          // 12,582,912 B
    bf16*  Wcat   = (bf16*)(ws + 12582912);               //  7,077,888 B (4608 x 768)
    bf16*  qkh    = (bf16*)(ws + 19660800);               // 25,165,824 B [8][12][2][1024][64]
    float* sums   = (float*)(ws + 44826624);              // rowsum 8192 | arow 98304
    float* rowsum = sums;
    float* arow   = sums + 8192;

    cast_all<<<9600, 256, 0, stream>>>(g, wq, wk, w_hn, g_bf, Wcat, rowsum, out);

    dim3 gg(64, 36);   // 8192/128 x 4608/128
    gemm_fused<<<gg, 256, 0, stream>>>(g_bf, Wcat, qkh, rowsum, beta);

    dim3 ga(8, 12, 8);   // qt, h, b
    attn_energy<<<ga, 256, 0, stream>>>(qkh, arow);

    finalize<<<416, 256, 0, stream>>>(sums, beta, out);
}

// Round 7
// 151.230 us; speedup vs baseline: 2.7169x; 1.1717x over previous
//
#include <hip/hip_runtime.h>
#include <hip/hip_bf16.h>
#include <stdint.h>
#include <stddef.h>

typedef __bf16 bf16;
typedef __bf16 bf16x4 __attribute__((ext_vector_type(4)));
typedef __bf16 bf16x8 __attribute__((ext_vector_type(8)));
typedef float  f32x4  __attribute__((ext_vector_type(4)));
typedef int    i32x8  __attribute__((ext_vector_type(8)));
typedef unsigned char u8;

#define LOG2E  1.44269504f
#define QSCALE 0.18033688f   /* 0.125 * log2(e) */
#define WSC    16.0f         /* weight prescale before fp8 cast */
#define IWSC   0.0625f       /* 1/16 */

// ---------------------------------------------------------------- helpers
__device__ __forceinline__ void gld_lds16(const void* gptr, void* lptr) {
    __builtin_amdgcn_global_load_lds(
        (const __attribute__((address_space(1))) unsigned int*)gptr,
        (__attribute__((address_space(3))) unsigned int*)lptr,
        16, 0, 0);
}

// ---------------------------------------------------------------- merged cast + zero
// fp8 e4m3 outputs. blocks [0,6144): g (scale 1) ; [6144,6720): wq ; [6720,7296): wk ;
// [7296,9600): w_hn  (weights prescaled by WSC=16 to escape e4m3 subnormals).
// blocks [0,8) also zero rowsum; block 0 thread 0 zeroes out[0].
__global__ void cast_all(const float* __restrict__ g, const float* __restrict__ wq,
                         const float* __restrict__ wk, const float* __restrict__ whn,
                         u8* __restrict__ g_f8, u8* __restrict__ Wcat,
                         float* __restrict__ rowsum, float* __restrict__ out) {
    int b = blockIdx.x, t = threadIdx.x;
    if (b < 8) {
        float4 z = {0.f, 0.f, 0.f, 0.f};
        *(float4*)(rowsum + (b * 256 + t) * 4) = z;
        if (b == 0 && t == 0) out[0] = 0.f;
    }
    const float* src; u8* dst; int off; float sc;
    if (b < 6144)      { src = g;   dst = g_f8;           off = 0;    sc = 1.0f; }
    else if (b < 6720) { src = wq;  dst = Wcat;           off = 6144; sc = WSC;  }
    else if (b < 7296) { src = wk;  dst = Wcat + 589824;  off = 6720; sc = WSC;  }
    else               { src = whn; dst = Wcat + 1179648; off = 7296; sc = WSC;  }
    int i = ((b - off) * 256 + t) * 4;
    float4 v = *(const float4*)(src + i);
    int p = __builtin_amdgcn_cvt_pk_fp8_f32(sc * v.x, sc * v.y, 0, false);
    p     = __builtin_amdgcn_cvt_pk_fp8_f32(sc * v.z, sc * v.w, p, true);
    *(int*)(dst + i) = p;
}

// ---------------------------------------------------------------- fused NT GEMM (MX-fp8)
// C_full[M,4608] = A[M,768] * Wcat[4608,768]^T, fp8 e4m3 in (weights x16), fp32 acc.
// mfma_scale_f32_16x16x128_f8f6f4 with unit scales (e8m0=127). BM=BN=128, BK=128 (bytes
// per row = 128, byte-identical LDS layout to the verified bf16 BK=64 tile).
// cols [0,1536): q/k -> bf16 qkh[b][h][{q,k}][1024][64], z-segs pre-swizzled (^(krow&7)),
//   q scaled QSCALE/16, k scaled 1/16.
// cols [1536,4608): Hopfield -> rowsum += exp2(beta*log2e/16 * acc) via atomicAdd.
__global__ void gemm_fused(const u8* __restrict__ A, const u8* __restrict__ Bm,
                           bf16* __restrict__ qkh, float* __restrict__ rowsum,
                           const float* __restrict__ beta_p) {
    __shared__ __align__(16) u8 As[128 * 128];   // 16 KB
    __shared__ __align__(16) u8 Bs[128 * 128];   // 16 KB
    const int t = threadIdx.x;
    const int w = t >> 6, l = t & 63;
    const int wm = (w >> 1) * 64, wn = (w & 1) * 64;
    const int tile_m = blockIdx.x * 128;
    const int tile_n = blockIdx.y * 128;

    f32x4 acc[4][4];
#pragma unroll
    for (int i = 0; i < 4; i++)
#pragma unroll
        for (int j = 0; j < 4; j++)
#pragma unroll
            for (int q = 0; q < 4; q++) acc[i][j][q] = 0.f;

    // staging: slot (i*256+t)*16B -> row i*32+(t>>3), seg t&7; global seg = (t&7)^(row&7)
    const int srow = t >> 3;               // 0..31
    const int sswz = (t & 7) ^ (srow & 7);
    const u8* gA = A  + (size_t)(tile_m + srow) * 768 + sswz * 16;
    const u8* gB = Bm + (size_t)(tile_n + srow) * 768 + sswz * 16;

    const int fr = l & 15, fg = l >> 4;
    // fragment segs (swizzled): k-bytes [fg*32, fg*32+32) = unswz segs {2fg, 2fg+1}
    const int s0 = ((2 * fg)     ^ (fr & 7)) * 16;
    const int s1 = ((2 * fg + 1) ^ (fr & 7)) * 16;

    for (int k0 = 0; k0 < 768; k0 += 128) {
#pragma unroll
        for (int i = 0; i < 4; i++) {
            gld_lds16(gA + (size_t)i * 32 * 768 + k0, As + (i * 256 + t) * 16);
            gld_lds16(gB + (size_t)i * 32 * 768 + k0, Bs + (i * 256 + t) * 16);
        }
        __builtin_amdgcn_s_waitcnt(0);
        __syncthreads();

        union F8 { uint4 q[2]; i32x8 v; };
        i32x8 af[4], bfr[4];
#pragma unroll
        for (int i = 0; i < 4; i++) {
            const u8* ra = As + (wm + i * 16 + fr) * 128;   // row&7 == fr&7
            const u8* rb = Bs + (wn + i * 16 + fr) * 128;
            F8 ua, ub;
            ua.q[0] = *(const uint4*)(ra + s0);
            ua.q[1] = *(const uint4*)(ra + s1);
            ub.q[0] = *(const uint4*)(rb + s0);
            ub.q[1] = *(const uint4*)(rb + s1);
            af[i] = ua.v; bfr[i] = ub.v;
        }
#pragma unroll
        for (int i = 0; i < 4; i++)
#pragma unroll
            for (int j = 0; j < 4; j++)
                acc[i][j] = __builtin_amdgcn_mfma_scale_f32_16x16x128_f8f6f4(
                    af[i], bfr[j], acc[i][j],
                    0, 0,                 // cbsz=fp8(e4m3), blgp=fp8(e4m3)
                    0, 0x7F7F7F7F,        // opsel_a, scale_a = 1.0 (e8m0 127)
                    0, 0x7F7F7F7F);       // opsel_b, scale_b = 1.0
        __syncthreads();
    }

    // C/D layout: col=lane&15, row=(lane>>4)*4+reg  [m89-verified, shape-determined]
    const int cr = fg * 4, cc = fr;

    if (tile_n < 1536) {
        const int tt = (tile_n >= 768);                    // 0 = q, 1 = k
        const int hh = (tile_n - tt * 768 + wn) >> 6;      // head (wn spans one head)
        const int bb = tile_m >> 10;
        const int m7 = tile_m & 1023;
        const float sc = (tt ? 1.0f : QSCALE) * IWSC;      // undo weight prescale
        bf16* base = qkh + ((size_t)(((bb * 12 + hh) * 2 + tt) * 1024 + m7) << 6);
#pragma unroll
        for (int i = 0; i < 4; i++)
#pragma unroll
            for (int r = 0; r < 4; r++) {
                int kr  = wm + i * 16 + cr + r;
                int swz = (cr + r) & 7;
#pragma unroll
                for (int j = 0; j < 4; j++) {
                    int z   = j * 16 + cc;                 // 0..63
                    int pos = (((z >> 3) ^ swz) << 3) | (z & 7);
                    base[(size_t)kr * 64 + pos] = (bf16)(sc * acc[i][j][r]);
                }
            }
    } else {
        const float sc2 = beta_p[0] * LOG2E * IWSC;
#pragma unroll
        for (int i = 0; i < 4; i++)
#pragma unroll
            for (int r = 0; r < 4; r++) {
                float s = 0.f;
#pragma unroll
                for (int j = 0; j < 4; j++) s += __builtin_amdgcn_exp2f(sc2 * acc[i][j][r]);
                s += __shfl_xor(s, 1, 16);
                s += __shfl_xor(s, 2, 16);
                s += __shfl_xor(s, 4, 16);
                s += __shfl_xor(s, 8, 16);
                if ((l & 15) == 0)
                    atomicAdd(&rowsum[tile_m + wm + i * 16 + cr + r], s);
            }
    }
}

// ---------------------------------------------------------------- attention exp-sums
// qkh[b][h][{q,k}][1024][64] bf16, z-segments pre-swizzled by (krow&7), q pre-scaled.
// grid (qt:8, h:12, b:8), 256 thr. Linear coalesced staging; double-buffered K chunks.
__global__ void __launch_bounds__(256, 4)
attn_energy(const bf16* __restrict__ qkh, float* __restrict__ arow) {
    __shared__ __align__(16) bf16 S[2][128 * 64];   // 32 KB
    const int t = threadIdx.x, w = t >> 6, l = t & 63;
    const int qt = blockIdx.x, h = blockIdx.y, b = blockIdx.z;
    const bf16* qp = qkh + ((size_t)((b * 12 + h) * 2 + 0) << 16) + qt * 128 * 64;
    const bf16* kp = qkh + ((size_t)((b * 12 + h) * 2 + 1) << 16);
    const int fr = l & 15, fg = l >> 4;

#pragma unroll
    for (int i = 0; i < 4; i++)
        gld_lds16(qp + (i * 256 + t) * 8, S[0] + (i * 256 + t) * 8);
    __builtin_amdgcn_s_waitcnt(0);
    __syncthreads();

    bf16x8 af[2][2];
#pragma unroll
    for (int mi = 0; mi < 2; mi++)
#pragma unroll
        for (int ks = 0; ks < 2; ks++) {
            int r = w * 32 + mi * 16 + fr;
            af[mi][ks] = *(const bf16x8*)(S[0] + r * 64 + ((ks * 4 + fg) ^ (fr & 7)) * 8);
        }

#pragma unroll
    for (int i = 0; i < 4; i++)
        gld_lds16(kp + (i * 256 + t) * 8, S[1] + (i * 256 + t) * 8);

    float rs[2][4] = {};
    for (int kc = 0; kc < 8; kc++) {
        const bf16* Sc = S[1 - (kc & 1)];
        __builtin_amdgcn_s_waitcnt(0);
        __syncthreads();
        if (kc < 7) {
            const bf16* src = kp + (kc + 1) * 128 * 64;
            bf16* dstb = (bf16*)S[kc & 1];
#pragma unroll
            for (int i = 0; i < 4; i++)
                gld_lds16(src + (i * 256 + t) * 8, dstb + (i * 256 + t) * 8);
        }
#pragma unroll
        for (int nt = 0; nt < 8; nt++) {
            int kr = nt * 16 + fr;
            bf16x8 b0 = *(const bf16x8*)(Sc + kr * 64 + ((0 + fg) ^ (fr & 7)) * 8);
            bf16x8 b1 = *(const bf16x8*)(Sc + kr * 64 + ((4 + fg) ^ (fr & 7)) * 8);
#pragma unroll
            for (int mi = 0; mi < 2; mi++) {
                f32x4 acc;
#pragma unroll
                for (int q = 0; q < 4; q++) acc[q] = 0.f;
                acc = __builtin_amdgcn_mfma_f32_16x16x32_bf16(af[mi][0], b0, acc, 0, 0, 0);
                acc = __builtin_amdgcn_mfma_f32_16x16x32_bf16(af[mi][1], b1, acc, 0, 0, 0);
#pragma unroll
                for (int r = 0; r < 4; r++) rs[mi][r] += __builtin_amdgcn_exp2f(acc[r]);
            }
        }
    }

    const int rowbase = (b * 12 + h) * 1024 + qt * 128 + w * 32;
#pragma unroll
    for (int mi = 0; mi < 2; mi++)
#pragma unroll
        for (int r = 0; r < 4; r++) {
            float v = rs[mi][r];
            v += __shfl_xor(v, 1, 16);
            v += __shfl_xor(v, 2, 16);
            v += __shfl_xor(v, 4, 16);
            v += __shfl_xor(v, 8, 16);
            if ((l & 15) == 0)
                arow[rowbase + mi * 16 + fg * 4 + r] = v;
        }
}

// ---------------------------------------------------------------- merged finalize
__global__ void finalize(const float* __restrict__ sums, const float* __restrict__ beta_p,
                         float* __restrict__ out) {
    __shared__ float wpart[4];
    const int t = threadIdx.x, w = t >> 6, l = t & 63;
    const int i = blockIdx.x * 256 + t;
    float v;
    if (i < 8192) v = (-1.f / beta_p[0]) * __logf(sums[i]);
    else          v = -8.f * __logf(sums[i]);
    for (int o = 32; o > 0; o >>= 1) v += __shfl_down(v, o, 64);
    if (l == 0) wpart[w] = v;
    __syncthreads();
    if (t == 0) atomicAdd(out, wpart[0] + wpart[1] + wpart[2] + wpart[3]);
}

// ---------------------------------------------------------------- launch
extern "C" void kernel_launch(void* const* d_in, const int* in_sizes, int n_in,
                              void* d_out, int out_size, void* d_ws, size_t ws_size,
                              hipStream_t stream) {
    const float* g    = (const float*)d_in[0];   // [8,1024,768]
    const float* wq   = (const float*)d_in[1];   // [12,64,768]
    const float* wk   = (const float*)d_in[2];   // [12,64,768]
    const float* w_hn = (const float*)d_in[3];   // [3072,768]
    const float* beta = (const float*)d_in[4];   // [1]
    float* out = (float*)d_out;

    char* ws = (char*)d_ws;
    u8*    g_f8   = (u8*)(ws);                            //  6,291,456 B
    u8*    Wcat   = (u8*)(ws + 6291456);                  //  3,538,944 B (4608 x 768)
    bf16*  qkh    = (bf16*)(ws + 9830400);                // 25,165,824 B [8][12][2][1024][64]
    float* sums   = (float*)(ws + 34996224);              // rowsum 8192 | arow 98304
    float* rowsum = sums;
    float* arow   = sums + 8192;

    cast_all<<<9600, 256, 0, stream>>>(g, wq, wk, w_hn, g_f8, Wcat, rowsum, out);

    dim3 gg(64, 36);   // 8192/128 x 4608/128
    gemm_fused<<<gg, 256, 0, stream>>>(g_f8, Wcat, qkh, rowsum, beta);

    dim3 ga(8, 12, 8);   // qt, h, b
    attn_energy<<<ga, 256, 0, stream>>>(qkh, arow);

    finalize<<<416, 256, 0, stream>>>(sums, beta, out);
}